// Round 1
// baseline (3168.267 us; speedup 1.0000x reference)
//
#include <hip/hip_runtime.h>
#include <math.h>

#define NN 40000
#define NE 640000
#define HH 128
#define OUTD 10

__device__ __forceinline__ float reluf(float x){ return x > 0.f ? x : 0.f; }

// ---------------- CSR build ----------------
__global__ void init_ws_kernel(int* cnt, float* diff_acc, int* flags) {
    int i = blockIdx.x*blockDim.x + threadIdx.x;
    if (i < NN) cnt[i] = 0;
    if (i < 32) diff_acc[i] = 0.f;
    if (i < 4)  flags[i] = 0;
}

__global__ void count_kernel(const int* __restrict__ ei, int* __restrict__ cnt) {
    int e = blockIdx.x*blockDim.x + threadIdx.x;
    if (e < NE) atomicAdd(&cnt[ei[NE + e]], 1);
}

__global__ void dinv_kernel(const int* __restrict__ cnt, float* __restrict__ dinv) {
    int i = blockIdx.x*blockDim.x + threadIdx.x;
    if (i < NN) dinv[i] = rsqrtf((float)(cnt[i] + 1));
}

__global__ __launch_bounds__(256) void scan_a_kernel(const int* __restrict__ cnt,
                                                     int* __restrict__ rowptr,
                                                     int* __restrict__ bsum) {
    __shared__ int sh[256];
    int t = threadIdx.x;
    int base = blockIdx.x * 1024 + t*4;
    int v[4]; int s = 0;
    #pragma unroll
    for (int q=0;q<4;q++){ int i = base+q; v[q] = (i < NN) ? (cnt[i] + 1) : 0; s += v[q]; }
    sh[t] = s; __syncthreads();
    for (int off=1; off<256; off<<=1){
        int x = (t>=off) ? sh[t-off] : 0;
        __syncthreads();
        sh[t] += x;
        __syncthreads();
    }
    int run = sh[t] - s;
    #pragma unroll
    for (int q=0;q<4;q++){ int i = base+q; if (i<NN) rowptr[i] = run; run += v[q]; }
    if (t==255) bsum[blockIdx.x] = sh[255];
}

__global__ void scan_b_kernel(int* bsum, int* rowptr, int nb) {
    if (threadIdx.x==0 && blockIdx.x==0){
        int run=0;
        for (int b=0;b<nb;b++){ int x=bsum[b]; bsum[b]=run; run+=x; }
        rowptr[NN] = run;
    }
}

__global__ void scan_c_kernel(int* __restrict__ rowptr, const int* __restrict__ bsum,
                              int* __restrict__ cnt) {
    int i = blockIdx.x*blockDim.x + threadIdx.x;
    if (i < NN){ rowptr[i] += bsum[i >> 10]; cnt[i] = 0; }
}

__global__ void scatter_kernel(const int* __restrict__ ei, const float* __restrict__ dinv,
                               const int* __restrict__ rowptr, int* __restrict__ cnt,
                               int* __restrict__ col, float* __restrict__ norme) {
    int i = blockIdx.x*blockDim.x + threadIdx.x;
    if (i >= NE + NN) return;
    int s, d;
    if (i < NE){ s = ei[i]; d = ei[NE+i]; } else { s = i - NE; d = s; }
    int pos = rowptr[d] + atomicAdd(&cnt[d], 1);
    col[pos] = s;
    norme[pos] = dinv[s]*dinv[d];
}

// ---------------- aggregation: out = A * X  (CSR by dst) ----------------
__global__ __launch_bounds__(256) void aggregate_kernel(const float* __restrict__ X,
    float* __restrict__ out,
    const int* __restrict__ rowptr, const int* __restrict__ col,
    const float* __restrict__ norme, const int* __restrict__ flag)
{
    if (flag && flag[0]) return;
    int node = blockIdx.x*4 + (threadIdx.x >> 6);
    if (node >= NN) return;
    int lane = threadIdx.x & 63;
    int c = lane*2;
    int e = rowptr[node], end = rowptr[node+1];
    float ax=0.f, ay=0.f;
    for (; e+2 <= end; e += 2){
        int s0 = col[e], s1 = col[e+1];
        float n0 = norme[e], n1 = norme[e+1];
        float2 v0 = *(const float2*)&X[(size_t)s0*HH + c];
        float2 v1 = *(const float2*)&X[(size_t)s1*HH + c];
        ax += n0*v0.x + n1*v1.x;
        ay += n0*v0.y + n1*v1.y;
    }
    if (e < end){
        int s0 = col[e]; float n0 = norme[e];
        float2 v0 = *(const float2*)&X[(size_t)s0*HH + c];
        ax += n0*v0.x; ay += n0*v0.y;
    }
    float2 r; r.x = ax; r.y = ay;
    *(float2*)&out[(size_t)node*HH + c] = r;
}

// ---------------- GEMM [N,128]@[128,128] with fused epilogue ----------------
// MODE 0: out = relu(A@W + b)
// MODE 1: out = out + relu(A@W + b)
// MODE 2: v = Xin - relu(A@W + b); diff += |v - out|; out = v   (flag-gated)
template<int MODE>
__global__ __launch_bounds__(256) void gemm_kernel(const float* __restrict__ A,
    const float* __restrict__ W, const float* __restrict__ bias,
    const float* __restrict__ Xin, float* __restrict__ out,
    float* __restrict__ diff_acc, const int* __restrict__ flag)
{
    if (MODE==2 && flag[0]) return;
    __shared__ float As[128][36];   // A tile transposed: As[k][row], padded
    __shared__ float Ws[32][128];   // W k-chunk
    __shared__ float wsum[4];
    int t = threadIdx.x;
    int rowbase = blockIdx.x * 32;

    // stage A tile (32 rows x 128 k), transposed
    {
        int f0 = t*4;
        #pragma unroll
        for (int q=0;q<4;q++){
            int f = f0 + q;                 // 0..1023
            int r = f >> 5;                 // 0..31
            int c4 = (f & 31) * 4;          // 0..124
            float4 g = *(const float4*)&A[(size_t)(rowbase + r)*HH + c4];
            As[c4+0][r] = g.x; As[c4+1][r] = g.y; As[c4+2][r] = g.z; As[c4+3][r] = g.w;
        }
    }

    int c4 = (t & 31)*4;
    int r4 = (t >> 5)*4;
    float acc[4][4];
    #pragma unroll
    for (int i=0;i<4;i++){
        #pragma unroll
        for (int j=0;j<4;j++) acc[i][j] = 0.f;
    }

    for (int kc=0; kc<4; ++kc){
        // stage W chunk rows kc*32 .. kc*32+31
        {
            int f0 = t*4;
            #pragma unroll
            for (int q=0;q<4;q++){
                int f = f0+q;
                int kk = f >> 5; int cc = (f & 31)*4;
                *(float4*)&Ws[kk][cc] = *(const float4*)&W[(size_t)(kc*32+kk)*HH + cc];
            }
        }
        __syncthreads();
        #pragma unroll 8
        for (int kk=0; kk<32; ++kk){
            float4 wv = *(const float4*)&Ws[kk][c4];
            float4 av = *(const float4*)&As[kc*32+kk][r4];
            acc[0][0] += av.x*wv.x; acc[0][1] += av.x*wv.y; acc[0][2] += av.x*wv.z; acc[0][3] += av.x*wv.w;
            acc[1][0] += av.y*wv.x; acc[1][1] += av.y*wv.y; acc[1][2] += av.y*wv.z; acc[1][3] += av.y*wv.w;
            acc[2][0] += av.z*wv.x; acc[2][1] += av.z*wv.y; acc[2][2] += av.z*wv.z; acc[2][3] += av.z*wv.w;
            acc[3][0] += av.w*wv.x; acc[3][1] += av.w*wv.y; acc[3][2] += av.w*wv.z; acc[3][3] += av.w*wv.w;
        }
        __syncthreads();
    }

    float4 bb = *(const float4*)&bias[c4];
    float local = 0.f;
    #pragma unroll
    for (int i=0;i<4;i++){
        size_t idx = (size_t)(rowbase + r4 + i)*HH + c4;
        float4 v;
        v.x = reluf(acc[i][0] + bb.x);
        v.y = reluf(acc[i][1] + bb.y);
        v.z = reluf(acc[i][2] + bb.z);
        v.w = reluf(acc[i][3] + bb.w);
        if (MODE == 0){
            *(float4*)&out[idx] = v;
        } else if (MODE == 1){
            float4 o = *(const float4*)&out[idx];
            o.x += v.x; o.y += v.y; o.z += v.z; o.w += v.w;
            *(float4*)&out[idx] = o;
        } else {
            float4 xi = *(const float4*)&Xin[idx];
            float4 xc = *(const float4*)&out[idx];
            float4 nv;
            nv.x = xi.x - v.x; nv.y = xi.y - v.y; nv.z = xi.z - v.z; nv.w = xi.w - v.w;
            local += fabsf(nv.x - xc.x) + fabsf(nv.y - xc.y) + fabsf(nv.z - xc.z) + fabsf(nv.w - xc.w);
            *(float4*)&out[idx] = nv;
        }
    }
    if (MODE == 2){
        #pragma unroll
        for (int off=32; off; off>>=1) local += __shfl_down(local, off);
        int lane = t & 63, w = t >> 6;
        if (lane==0) wsum[w] = local;
        __syncthreads();
        if (t==0) atomicAdd(diff_acc, wsum[0]+wsum[1]+wsum[2]+wsum[3]);
    }
}

__global__ void flag_update_kernel(const float* __restrict__ dacc, int* __restrict__ flag){
    // mean over N*H < 1e-4  <=>  sum < 1e-4 * 40000 * 128 = 512
    if (dacc[0] < 512.0f) flag[0] = 1;
}

// ---------------- fused LN + MLP head ----------------
__global__ __launch_bounds__(256) void final_kernel(const float* __restrict__ zf,
    const float* __restrict__ zb,
    const float* __restrict__ lng, const float* __restrict__ lnb,
    const float* __restrict__ W1, const float* __restrict__ b1,
    const float* __restrict__ W2, const float* __restrict__ b2,
    float* __restrict__ out)
{
    __shared__ float zs[8][256];
    __shared__ float h1s[8][128];
    __shared__ float Wc[64][128];
    int t = threadIdx.x;
    int node0 = blockIdx.x * 8;
    // load z = [zf | zb] for 8 nodes
    {
        int n = t >> 5; int cc = (t & 31)*4;
        *(float4*)&zs[n][cc]     = *(const float4*)&zf[(size_t)(node0+n)*HH + cc];
        *(float4*)&zs[n][128+cc] = *(const float4*)&zb[(size_t)(node0+n)*HH + cc];
    }
    __syncthreads();
    // LayerNorm over 256: wave w handles nodes 2w, 2w+1
    {
        int w = t >> 6, lane = t & 63;
        for (int nn = w*2; nn <= w*2+1; ++nn){
            float4 v = *(float4*)&zs[nn][lane*4];
            float s  = v.x+v.y+v.z+v.w;
            float sq = v.x*v.x+v.y*v.y+v.z*v.z+v.w*v.w;
            #pragma unroll
            for (int off=32; off; off>>=1){ s += __shfl_down(s, off); sq += __shfl_down(sq, off); }
            s = __shfl(s, 0); sq = __shfl(sq, 0);
            float mu = s * (1.f/256.f);
            float var = sq * (1.f/256.f) - mu*mu;
            float rs = rsqrtf(var + 1e-5f);
            float4 g = *(const float4*)&lng[lane*4];
            float4 b = *(const float4*)&lnb[lane*4];
            v.x = (v.x-mu)*rs*g.x + b.x;
            v.y = (v.y-mu)*rs*g.y + b.y;
            v.z = (v.z-mu)*rs*g.z + b.z;
            v.w = (v.w-mu)*rs*g.w + b.w;
            *(float4*)&zs[nn][lane*4] = v;
        }
    }
    __syncthreads();
    // layer 1: h1 = relu(z @ W1 + b1), W1 [256,128] staged in 64-row chunks
    int n = t >> 5; int j0 = t & 31;
    float a1[4] = {0.f,0.f,0.f,0.f};
    for (int kc=0; kc<4; ++kc){
        #pragma unroll
        for (int q=0;q<8;q++){
            int f = t*8+q;                  // 0..2047 float4s
            int kk = f >> 5; int cc = (f & 31)*4;
            *(float4*)&Wc[kk][cc] = *(const float4*)&W1[(size_t)(kc*64+kk)*HH + cc];
        }
        __syncthreads();
        #pragma unroll 8
        for (int kk=0; kk<64; ++kk){
            float zv = zs[n][kc*64+kk];
            a1[0] += zv * Wc[kk][j0];
            a1[1] += zv * Wc[kk][j0+32];
            a1[2] += zv * Wc[kk][j0+64];
            a1[3] += zv * Wc[kk][j0+96];
        }
        __syncthreads();
    }
    #pragma unroll
    for (int q=0;q<4;q++) h1s[n][j0+32*q] = reluf(a1[q] + b1[j0+32*q]);
    __syncthreads();
    // layer 2: out = h1 @ W2 + b2  (128 -> 10), 80 outputs per block
    if (t < 80){
        int nn = t/10, o = t - nn*10;
        float a = b2[o];
        #pragma unroll 16
        for (int j=0;j<HH;j++) a += h1s[nn][j] * W2[j*OUTD + o];
        out[(size_t)(node0+nn)*OUTD + o] = a;
    }
}

// ---------------- host ----------------
extern "C" void kernel_launch(void* const* d_in, const int* in_sizes, int n_in,
                              void* d_out, int out_size, void* d_ws, size_t ws_size,
                              hipStream_t stream)
{
    const float* x    = (const float*)d_in[0];
    const int*   ei   = (const int*)d_in[1];
    const float* W_in = (const float*)d_in[2];
    const float* b_in = (const float*)d_in[3];
    const float* W0   = (const float*)d_in[4];
    const float* b0   = (const float*)d_in[5];
    const float* W1   = (const float*)d_in[6];
    const float* b1   = (const float*)d_in[7];
    const float* lng  = (const float*)d_in[8];
    const float* lnb  = (const float*)d_in[9];
    const float* Wo1  = (const float*)d_in[10];
    const float* bo1  = (const float*)d_in[11];
    const float* Wo2  = (const float*)d_in[12];
    const float* bo2  = (const float*)d_in[13];
    float* out = (float*)d_out;

    char* p = (char*)d_ws;
    auto alloc = [&](size_t bytes)->char* {
        char* r = p; p += (bytes + 255) & ~(size_t)255; return r;
    };
    float* dinv   = (float*)alloc((size_t)NN*4);
    int*   cnt    = (int*)  alloc((size_t)NN*4);
    int*   rowptr = (int*)  alloc((size_t)(NN+1)*4);
    int*   bsum   = (int*)  alloc(64*4);
    int*   col    = (int*)  alloc((size_t)(NE+NN)*4);
    float* norme  = (float*)alloc((size_t)(NE+NN)*4);
    int*   flags  = (int*)  alloc(4*4);
    float* dacc   = (float*)alloc(32*4);
    float* h      = (float*)alloc((size_t)NN*HH*4);
    float* zf     = (float*)alloc((size_t)NN*HH*4);
    float* zbB    = (float*)alloc((size_t)NN*HH*4);
    float* agg    = (float*)alloc((size_t)NN*HH*4);

    init_ws_kernel<<<(NN+255)/256, 256, 0, stream>>>(cnt, dacc, flags);
    count_kernel<<<(NE+255)/256, 256, 0, stream>>>(ei, cnt);
    dinv_kernel<<<(NN+255)/256, 256, 0, stream>>>(cnt, dinv);
    int nb = (NN+1023)/1024;
    scan_a_kernel<<<nb, 256, 0, stream>>>(cnt, rowptr, bsum);
    scan_b_kernel<<<1, 64, 0, stream>>>(bsum, rowptr, nb);
    scan_c_kernel<<<(NN+255)/256, 256, 0, stream>>>(rowptr, bsum, cnt);
    scatter_kernel<<<(NE+NN+255)/256, 256, 0, stream>>>(ei, dinv, rowptr, cnt, col, norme);

    // h = relu(x @ W_in + b_in)
    gemm_kernel<0><<<NN/32, 256, 0, stream>>>(x, W_in, b_in, nullptr, h, nullptr, nullptr);
    hipMemcpyAsync(zf, h, (size_t)NN*HH*4, hipMemcpyDeviceToDevice, stream);

    // forward residual blocks
    for (int d=0; d<4; ++d){
        const float* Wd = (d & 1) ? W1 : W0;
        const float* bd = (d & 1) ? b1 : b0;
        aggregate_kernel<<<NN/4, 256, 0, stream>>>(zf, agg, rowptr, col, norme, nullptr);
        gemm_kernel<1><<<NN/32, 256, 0, stream>>>(agg, Wd, bd, nullptr, zf, nullptr, nullptr);
    }

    // inverse fixed-point blocks (ping-pong h <-> zbB)
    float* pin = h; float* pxc = zbB;
    for (int i=0; i<4; ++i){
        const float* Wi = (i & 1) ? W0 : W1;   // i%2==0 -> W1, i%2==1 -> W0
        const float* bi = (i & 1) ? b0 : b1;
        hipMemcpyAsync(pxc, pin, (size_t)NN*HH*4, hipMemcpyDeviceToDevice, stream);
        for (int tt=0; tt<8; ++tt){
            int slot = i*8 + tt;
            aggregate_kernel<<<NN/4, 256, 0, stream>>>(pxc, agg, rowptr, col, norme, flags+i);
            gemm_kernel<2><<<NN/32, 256, 0, stream>>>(agg, Wi, bi, pin, pxc, dacc+slot, flags+i);
            flag_update_kernel<<<1, 1, 0, stream>>>(dacc+slot, flags+i);
        }
        float* tmp = pin; pin = pxc; pxc = tmp;
    }

    final_kernel<<<NN/8, 256, 0, stream>>>(zf, pin, lng, lnb, Wo1, bo1, Wo2, bo2, out);
}

// Round 2
// 2478.129 us; speedup vs baseline: 1.2785x; 1.2785x over previous
//
#include <hip/hip_runtime.h>
#include <math.h>

#define NN 40000
#define NE 640000
#define HH 128
#define OUTD 10

typedef __attribute__((ext_vector_type(8))) short short8;
typedef __attribute__((ext_vector_type(4))) float f32x4;

__device__ __forceinline__ float reluf(float x){ return x > 0.f ? x : 0.f; }
__device__ __forceinline__ float bf2f(unsigned short b){
    union { unsigned u; float f; } v; v.u = ((unsigned)b) << 16; return v.f;
}
__device__ __forceinline__ unsigned short f2bf(float f){
    unsigned u = __float_as_uint(f);
    u += 0x7fffu + ((u >> 16) & 1u);
    return (unsigned short)(u >> 16);
}

// ---------------- CSR build ----------------
__global__ void init_ws_kernel(int* cnt, float* diff_acc, unsigned int* ctr, int* flags) {
    int i = blockIdx.x*blockDim.x + threadIdx.x;
    if (i < NN) cnt[i] = 0;
    if (i < 32) { diff_acc[i] = 0.f; ctr[i] = 0u; }
    if (i < 4)  flags[i] = 0;
}

__global__ void count_kernel(const int* __restrict__ ei, int* __restrict__ cnt) {
    int e = blockIdx.x*blockDim.x + threadIdx.x;
    if (e < NE) atomicAdd(&cnt[ei[NE + e]], 1);
}

__global__ void dinv_kernel(const int* __restrict__ cnt, float* __restrict__ dinv) {
    int i = blockIdx.x*blockDim.x + threadIdx.x;
    if (i < NN) dinv[i] = rsqrtf((float)(cnt[i] + 1));
}

__global__ __launch_bounds__(256) void scan_a_kernel(const int* __restrict__ cnt,
                                                     int* __restrict__ rowptr,
                                                     int* __restrict__ bsum) {
    __shared__ int sh[256];
    int t = threadIdx.x;
    int base = blockIdx.x * 1024 + t*4;
    int v[4]; int s = 0;
    #pragma unroll
    for (int q=0;q<4;q++){ int i = base+q; v[q] = (i < NN) ? (cnt[i] + 1) : 0; s += v[q]; }
    sh[t] = s; __syncthreads();
    for (int off=1; off<256; off<<=1){
        int x = (t>=off) ? sh[t-off] : 0;
        __syncthreads();
        sh[t] += x;
        __syncthreads();
    }
    int run = sh[t] - s;
    #pragma unroll
    for (int q=0;q<4;q++){ int i = base+q; if (i<NN) rowptr[i] = run; run += v[q]; }
    if (t==255) bsum[blockIdx.x] = sh[255];
}

__global__ void scan_b_kernel(int* bsum, int* rowptr, int nb) {
    if (threadIdx.x==0 && blockIdx.x==0){
        int run=0;
        for (int b=0;b<nb;b++){ int x=bsum[b]; bsum[b]=run; run+=x; }
        rowptr[NN] = run;
    }
}

__global__ void scan_c_kernel(int* __restrict__ rowptr, const int* __restrict__ bsum,
                              int* __restrict__ cnt) {
    int i = blockIdx.x*blockDim.x + threadIdx.x;
    if (i < NN){ rowptr[i] += bsum[i >> 10]; cnt[i] = 0; }
}

__global__ void scatter_kernel(const int* __restrict__ ei, const float* __restrict__ dinv,
                               const int* __restrict__ rowptr, int* __restrict__ cnt,
                               int* __restrict__ col, float* __restrict__ norme) {
    int i = blockIdx.x*blockDim.x + threadIdx.x;
    if (i >= NE + NN) return;
    int s, d;
    if (i < NE){ s = ei[i]; d = ei[NE+i]; } else { s = i - NE; d = s; }
    int pos = rowptr[d] + atomicAdd(&cnt[d], 1);
    col[pos] = s;
    norme[pos] = dinv[s]*dinv[d];
}

// ---------------- weight prep: transpose + bf16 ----------------
__global__ void prep_weights_kernel(const float* __restrict__ Win, const float* __restrict__ W0,
    const float* __restrict__ W1, const float* __restrict__ Wo1,
    unsigned short* WinT, unsigned short* W0T, unsigned short* W1T, unsigned short* Wo1T)
{
    int b = blockIdx.x, t = threadIdx.x;
    const float* src = (b==0)?Win : (b==1)?W0 : (b==2)?W1 : Wo1;
    unsigned short* dst = (b==0)?WinT : (b==1)?W0T : (b==2)?W1T : Wo1T;
    int K = (b==3)?256:128;
    int total = K*HH;
    for (int i=t; i<total; i+=256){
        int k = i >> 7, c = i & 127;
        dst[c*K + k] = f2bf(src[i]);
    }
}

__global__ void convert_x_kernel(const float* __restrict__ x, unsigned short* __restrict__ xb){
    int i = (blockIdx.x*256 + threadIdx.x)*8;    // 2500 blocks x 256 x 8 = 5,120,000 exactly
    float4 f0 = *(const float4*)&x[i];
    float4 f1 = *(const float4*)&x[i+4];
    uint4 r;
    r.x = (unsigned)f2bf(f0.x) | ((unsigned)f2bf(f0.y)<<16);
    r.y = (unsigned)f2bf(f0.z) | ((unsigned)f2bf(f0.w)<<16);
    r.z = (unsigned)f2bf(f1.x) | ((unsigned)f2bf(f1.y)<<16);
    r.w = (unsigned)f2bf(f1.z) | ((unsigned)f2bf(f1.w)<<16);
    *(uint4*)&xb[i] = r;
}

// ---------------- aggregation: outb = A * Xb  (CSR by dst, bf16 in/out) ----------------
__global__ __launch_bounds__(256) void aggregate_kernel(const unsigned short* __restrict__ Xb,
    unsigned short* __restrict__ outb,
    const int* __restrict__ rowptr, const int* __restrict__ col,
    const float* __restrict__ norme, const int* __restrict__ flag)
{
    if (flag && flag[0]) return;
    int node = blockIdx.x*8 + (threadIdx.x >> 5);
    int lane = threadIdx.x & 31;
    int c = lane*4;
    int e = rowptr[node], end = rowptr[node+1];
    float a0=0.f,a1=0.f,a2=0.f,a3=0.f;
    for (; e+2 <= end; e += 2){
        int s0 = col[e], s1 = col[e+1];
        float n0 = norme[e], n1 = norme[e+1];
        uint2 v0 = *(const uint2*)&Xb[(size_t)s0*HH + c];
        uint2 v1 = *(const uint2*)&Xb[(size_t)s1*HH + c];
        a0 += n0*bf2f((unsigned short)(v0.x&0xffffu)) + n1*bf2f((unsigned short)(v1.x&0xffffu));
        a1 += n0*bf2f((unsigned short)(v0.x>>16))     + n1*bf2f((unsigned short)(v1.x>>16));
        a2 += n0*bf2f((unsigned short)(v0.y&0xffffu)) + n1*bf2f((unsigned short)(v1.y&0xffffu));
        a3 += n0*bf2f((unsigned short)(v0.y>>16))     + n1*bf2f((unsigned short)(v1.y>>16));
    }
    if (e < end){
        int s0 = col[e]; float n0 = norme[e];
        uint2 v0 = *(const uint2*)&Xb[(size_t)s0*HH + c];
        a0 += n0*bf2f((unsigned short)(v0.x&0xffffu));
        a1 += n0*bf2f((unsigned short)(v0.x>>16));
        a2 += n0*bf2f((unsigned short)(v0.y&0xffffu));
        a3 += n0*bf2f((unsigned short)(v0.y>>16));
    }
    uint2 r;
    r.x = (unsigned)f2bf(a0) | ((unsigned)f2bf(a1)<<16);
    r.y = (unsigned)f2bf(a2) | ((unsigned)f2bf(a3)<<16);
    *(uint2*)&outb[(size_t)node*HH + c] = r;
}

// ---------------- MFMA GEMM [N,128]@[128,128] with fused epilogue ----------------
// MODE 0: out = relu(G+b)                       (input layer, A = x_b)
// MODE 1: out = Xin + relu(G+b)                 (forward d=0)
// MODE 2: out = out + relu(G+b)                 (forward d>=1, in place)
// MODE 3: v = Xin - relu(G+b); diff += |v-XC|; out = v; fused flag update
template<int MODE>
__global__ __launch_bounds__(256) void gemm_kernel(
    const unsigned short* __restrict__ Ab,   // [N][128] bf16
    const unsigned short* __restrict__ Wt,   // [128 col][128 k] bf16 (W transposed)
    const float* __restrict__ bias,
    const float* __restrict__ Xin,
    const float* __restrict__ XC,
    float* __restrict__ out,
    unsigned short* __restrict__ outb,
    float* __restrict__ dacc, unsigned int* __restrict__ ctr,
    int* __restrict__ flag)
{
    if (MODE==3 && flag[0]) return;
    int t = threadIdx.x;
    int w = t >> 6, lane = t & 63;
    int l15 = lane & 15, l4 = lane >> 4;
    int colbase = w*32;

    // preload B fragments (whole 128x32 col-strip of W^T) into registers
    short8 bfr[4][2];
    #pragma unroll
    for (int kc=0;kc<4;kc++){
        #pragma unroll
        for (int cc=0;cc<2;cc++){
            int cl = colbase + cc*16 + l15;
            bfr[kc][cc] = *(const short8*)&Wt[(size_t)cl*HH + kc*32 + l4*8];
        }
    }
    float b0 = bias[colbase + l15];
    float b1 = bias[colbase + 16 + l15];

    int tile0 = blockIdx.x*8;
    int tile_end = tile0 + 8; if (tile_end > 2500) tile_end = 2500;
    float ldiff = 0.f;

    for (int tt = tile0; tt < tile_end; ++tt){
        int row = tt*16 + l15;
        const unsigned short* ap = &Ab[(size_t)row*HH + l4*8];
        f32x4 acc0 = {0.f,0.f,0.f,0.f};
        f32x4 acc1 = {0.f,0.f,0.f,0.f};
        #pragma unroll
        for (int kc=0;kc<4;kc++){
            short8 a = *(const short8*)(ap + kc*32);
            acc0 = __builtin_amdgcn_mfma_f32_16x16x32_bf16(a, bfr[kc][0], acc0, 0,0,0);
            acc1 = __builtin_amdgcn_mfma_f32_16x16x32_bf16(a, bfr[kc][1], acc1, 0,0,0);
        }
        int r0 = tt*16 + l4*4;
        #pragma unroll
        for (int r=0;r<4;r++){
            int rw = r0 + r;
            size_t i0 = (size_t)rw*HH + colbase + l15;
            size_t i1 = i0 + 16;
            float v0 = reluf(acc0[r] + b0);
            float v1 = reluf(acc1[r] + b1);
            if (MODE==1){ v0 = Xin[i0] + v0; v1 = Xin[i1] + v1; }
            else if (MODE==2){ v0 = out[i0] + v0; v1 = out[i1] + v1; }
            else if (MODE==3){
                float xc0 = XC[i0], xc1 = XC[i1];
                v0 = Xin[i0] - v0; v1 = Xin[i1] - v1;
                ldiff += fabsf(v0-xc0) + fabsf(v1-xc1);
            }
            out[i0]=v0; out[i1]=v1;
            outb[i0]=f2bf(v0); outb[i1]=f2bf(v1);
        }
    }

    if (MODE==3){
        #pragma unroll
        for (int off=32; off; off>>=1) ldiff += __shfl_down(ldiff, off);
        __shared__ float wsum[4];
        if (lane==0) wsum[w] = ldiff;
        __syncthreads();
        if (t==0){
            atomicAdd(dacc, wsum[0]+wsum[1]+wsum[2]+wsum[3]);
            __threadfence();
            unsigned prev = atomicAdd(ctr, 1u);
            if (prev == gridDim.x - 1){
                __threadfence();
                // mean over N*H < 1e-4  <=>  sum < 512
                if (*(volatile float*)dacc < 512.0f) *flag = 1;
            }
        }
    }
}

__device__ __forceinline__ float u_lo(unsigned u){ return bf2f((unsigned short)(u & 0xffffu)); }
__device__ __forceinline__ float u_hi(unsigned u){ return bf2f((unsigned short)(u >> 16)); }

// ---------------- fused LN + MLP head (MFMA) ----------------
__global__ __launch_bounds__(256) void final_kernel(
    const unsigned short* __restrict__ zfb, const unsigned short* __restrict__ zbb,
    const float* __restrict__ lng, const float* __restrict__ lnb,
    const unsigned short* __restrict__ Wo1t,  // [128 col][256 k] bf16
    const float* __restrict__ bo1,
    const float* __restrict__ Wo2, const float* __restrict__ bo2,
    float* __restrict__ out)
{
    __shared__ unsigned short zs[64*256];      // swizzled bf16 z
    __shared__ unsigned short h1s[64*132];     // bf16 h1, padded stride
    int t = threadIdx.x;
    int node0 = blockIdx.x * 64;

    // ---- phase 1: load + LayerNorm (4 threads per node, 64 cols each) ----
    {
        int n = t >> 2, q = t & 3;
        const unsigned short* srcp = (q < 2) ? &zfb[(size_t)(node0+n)*HH + q*64]
                                             : &zbb[(size_t)(node0+n)*HH + (q-2)*64];
        uint4 pk[8];
        float s = 0.f, sq = 0.f;
        #pragma unroll
        for (int m=0;m<8;m++){
            pk[m] = *(const uint4*)&srcp[m*8];
            float f0=u_lo(pk[m].x), f1=u_hi(pk[m].x), f2=u_lo(pk[m].y), f3=u_hi(pk[m].y);
            float f4=u_lo(pk[m].z), f5=u_hi(pk[m].z), f6=u_lo(pk[m].w), f7=u_hi(pk[m].w);
            s  += f0+f1+f2+f3+f4+f5+f6+f7;
            sq += f0*f0+f1*f1+f2*f2+f3*f3+f4*f4+f5*f5+f6*f6+f7*f7;
        }
        s  += __shfl_xor(s,1);  s  += __shfl_xor(s,2);
        sq += __shfl_xor(sq,1); sq += __shfl_xor(sq,2);
        float mu = s * (1.f/256.f);
        float var = sq * (1.f/256.f) - mu*mu;
        float rs = rsqrtf(var + 1e-5f);
        int c0 = q*64;
        #pragma unroll
        for (int m=0;m<8;m++){
            int c = c0 + m*8;
            float4 g0 = *(const float4*)&lng[c];
            float4 g1 = *(const float4*)&lng[c+4];
            float4 bb0 = *(const float4*)&lnb[c];
            float4 bb1 = *(const float4*)&lnb[c+4];
            float f0=(u_lo(pk[m].x)-mu)*rs*g0.x+bb0.x;
            float f1=(u_hi(pk[m].x)-mu)*rs*g0.y+bb0.y;
            float f2=(u_lo(pk[m].y)-mu)*rs*g0.z+bb0.z;
            float f3=(u_hi(pk[m].y)-mu)*rs*g0.w+bb0.w;
            float f4=(u_lo(pk[m].z)-mu)*rs*g1.x+bb1.x;
            float f5=(u_hi(pk[m].z)-mu)*rs*g1.y+bb1.y;
            float f6=(u_lo(pk[m].w)-mu)*rs*g1.z+bb1.z;
            float f7=(u_hi(pk[m].w)-mu)*rs*g1.w+bb1.w;
            uint4 r;
            r.x = (unsigned)f2bf(f0) | ((unsigned)f2bf(f1)<<16);
            r.y = (unsigned)f2bf(f2) | ((unsigned)f2bf(f3)<<16);
            r.z = (unsigned)f2bf(f4) | ((unsigned)f2bf(f5)<<16);
            r.w = (unsigned)f2bf(f6) | ((unsigned)f2bf(f7)<<16);
            int idx = n*256 + c;                    // ushort units, 8-aligned
            *(uint4*)&zs[idx ^ ((n&7)<<3)] = r;     // XOR swizzle (16B granularity)
        }
    }
    __syncthreads();

    // ---- phase 2: h1 = relu(z @ Wo1 + bo1) via MFMA ----
    {
        int w = t >> 6, lane = t & 63;
        int l15 = lane & 15, l4 = lane >> 4;
        short8 bfr[8][2];
        #pragma unroll
        for (int kc=0;kc<8;kc++){
            #pragma unroll
            for (int cc=0;cc<2;cc++){
                int cl = w*32 + cc*16 + l15;
                bfr[kc][cc] = *(const short8*)&Wo1t[(size_t)cl*256 + kc*32 + l4*8];
            }
        }
        float bb0 = bo1[w*32 + l15];
        float bb1 = bo1[w*32 + 16 + l15];
        #pragma unroll
        for (int rt=0;rt<4;rt++){
            f32x4 acc0 = {0.f,0.f,0.f,0.f};
            f32x4 acc1 = {0.f,0.f,0.f,0.f};
            int row = rt*16 + l15;
            int rowswz = (row&7)<<3;
            #pragma unroll
            for (int kc=0;kc<8;kc++){
                int idx = row*256 + kc*32 + l4*8;
                short8 a = *(const short8*)&zs[idx ^ rowswz];
                acc0 = __builtin_amdgcn_mfma_f32_16x16x32_bf16(a, bfr[kc][0], acc0, 0,0,0);
                acc1 = __builtin_amdgcn_mfma_f32_16x16x32_bf16(a, bfr[kc][1], acc1, 0,0,0);
            }
            #pragma unroll
            for (int r=0;r<4;r++){
                int rw = rt*16 + l4*4 + r;
                h1s[rw*132 + w*32 + l15]      = f2bf(reluf(acc0[r] + bb0));
                h1s[rw*132 + w*32 + 16 + l15] = f2bf(reluf(acc1[r] + bb1));
            }
        }
    }
    __syncthreads();

    // ---- phase 3: out = h1 @ Wo2 + bo2 (128 -> 10) ----
    for (int item = t; item < 64*OUTD; item += 256){
        int n = item / OUTD, o = item - n*OUTD;
        float s = bo2[o];
        #pragma unroll 4
        for (int k=0;k<HH;k++) s += bf2f(h1s[n*132+k]) * Wo2[k*OUTD + o];
        out[(size_t)(node0+n)*OUTD + o] = s;
    }
}

// ---------------- host ----------------
extern "C" void kernel_launch(void* const* d_in, const int* in_sizes, int n_in,
                              void* d_out, int out_size, void* d_ws, size_t ws_size,
                              hipStream_t stream)
{
    const float* x    = (const float*)d_in[0];
    const int*   ei   = (const int*)d_in[1];
    const float* W_in = (const float*)d_in[2];
    const float* b_in = (const float*)d_in[3];
    const float* W0   = (const float*)d_in[4];
    const float* b0   = (const float*)d_in[5];
    const float* W1   = (const float*)d_in[6];
    const float* b1   = (const float*)d_in[7];
    const float* lng  = (const float*)d_in[8];
    const float* lnb  = (const float*)d_in[9];
    const float* Wo1  = (const float*)d_in[10];
    const float* bo1  = (const float*)d_in[11];
    const float* Wo2  = (const float*)d_in[12];
    const float* bo2  = (const float*)d_in[13];
    float* out = (float*)d_out;

    char* p = (char*)d_ws;
    auto alloc = [&](size_t bytes)->char* {
        char* r = p; p += (bytes + 255) & ~(size_t)255; return r;
    };
    float* dinv   = (float*)alloc((size_t)NN*4);
    int*   cnt    = (int*)  alloc((size_t)NN*4);
    int*   rowptr = (int*)  alloc((size_t)(NN+1)*4);
    int*   bsum   = (int*)  alloc(64*4);
    int*   col    = (int*)  alloc((size_t)(NE+NN)*4);
    float* norme  = (float*)alloc((size_t)(NE+NN)*4);
    int*   flags  = (int*)  alloc(4*4);
    float* dacc   = (float*)alloc(32*4);
    unsigned int* ctr = (unsigned int*)alloc(32*4);
    unsigned short* x_b   = (unsigned short*)alloc((size_t)NN*HH*2);
    unsigned short* agg_b = (unsigned short*)alloc((size_t)NN*HH*2);
    unsigned short* WinT  = (unsigned short*)alloc((size_t)HH*HH*2);
    unsigned short* W0T   = (unsigned short*)alloc((size_t)HH*HH*2);
    unsigned short* W1T   = (unsigned short*)alloc((size_t)HH*HH*2);
    unsigned short* Wo1T  = (unsigned short*)alloc((size_t)256*HH*2);
    float* h   = (float*)alloc((size_t)NN*HH*4);
    float* zf  = (float*)alloc((size_t)NN*HH*4);
    float* zbB = (float*)alloc((size_t)NN*HH*4);
    unsigned short* h_b   = (unsigned short*)alloc((size_t)NN*HH*2);
    unsigned short* zf_b  = (unsigned short*)alloc((size_t)NN*HH*2);
    unsigned short* zbB_b = (unsigned short*)alloc((size_t)NN*HH*2);

    init_ws_kernel<<<(NN+255)/256, 256, 0, stream>>>(cnt, dacc, ctr, flags);
    count_kernel<<<(NE+255)/256, 256, 0, stream>>>(ei, cnt);
    dinv_kernel<<<(NN+255)/256, 256, 0, stream>>>(cnt, dinv);
    int nb = (NN+1023)/1024;
    scan_a_kernel<<<nb, 256, 0, stream>>>(cnt, rowptr, bsum);
    scan_b_kernel<<<1, 64, 0, stream>>>(bsum, rowptr, nb);
    scan_c_kernel<<<(NN+255)/256, 256, 0, stream>>>(rowptr, bsum, cnt);
    scatter_kernel<<<(NE+NN+255)/256, 256, 0, stream>>>(ei, dinv, rowptr, cnt, col, norme);
    convert_x_kernel<<<2500, 256, 0, stream>>>(x, x_b);
    prep_weights_kernel<<<4, 256, 0, stream>>>(W_in, W0, W1, Wo1, WinT, W0T, W1T, Wo1T);

    const int GG = 313;   // ceil(2500 tiles / 8)

    // h = relu(x @ W_in + b_in)
    gemm_kernel<0><<<GG, 256, 0, stream>>>(x_b, WinT, b_in, nullptr, nullptr, h, h_b,
                                           nullptr, nullptr, nullptr);

    // forward residual blocks
    for (int d=0; d<4; ++d){
        const unsigned short* Wd = (d & 1) ? W1T : W0T;
        const float* bd = (d & 1) ? b1 : b0;
        const unsigned short* src_b = (d == 0) ? h_b : zf_b;
        aggregate_kernel<<<NN/8, 256, 0, stream>>>(src_b, agg_b, rowptr, col, norme, nullptr);
        if (d == 0)
            gemm_kernel<1><<<GG, 256, 0, stream>>>(agg_b, Wd, bd, h, nullptr, zf, zf_b,
                                                   nullptr, nullptr, nullptr);
        else
            gemm_kernel<2><<<GG, 256, 0, stream>>>(agg_b, Wd, bd, nullptr, nullptr, zf, zf_b,
                                                   nullptr, nullptr, nullptr);
    }

    // inverse fixed-point blocks (ping-pong h <-> zbB, no memcpy: tt=0 reads pin)
    float* pin = h;   unsigned short* pinb = h_b;
    float* pxc = zbB; unsigned short* pxcb = zbB_b;
    for (int i=0; i<4; ++i){
        const unsigned short* Wi = (i & 1) ? W0T : W1T;
        const float* bi = (i & 1) ? b0 : b1;
        for (int tt=0; tt<8; ++tt){
            int slot = i*8 + tt;
            const unsigned short* src_b = (tt==0) ? pinb : pxcb;
            const float* xc = (tt==0) ? pin : pxc;
            aggregate_kernel<<<NN/8, 256, 0, stream>>>(src_b, agg_b, rowptr, col, norme, flags+i);
            gemm_kernel<3><<<GG, 256, 0, stream>>>(agg_b, Wi, bi, pin, xc, pxc, pxcb,
                                                   dacc+slot, ctr+slot, flags+i);
        }
        float* tf = pin; pin = pxc; pxc = tf;
        unsigned short* tb = pinb; pinb = pxcb; pxcb = tb;
    }

    final_kernel<<<NN/64, 256, 0, stream>>>(zf_b, pinb, lng, lnb, Wo1T, bo1, Wo2, bo2, out);
}

// Round 4
// 1616.982 us; speedup vs baseline: 1.9594x; 1.5326x over previous
//
#include <hip/hip_runtime.h>
#include <math.h>

#define NN 40000
#define NE 640000
#define HH 128
#define OUTD 10

typedef __attribute__((ext_vector_type(8))) short short8;
typedef __attribute__((ext_vector_type(4))) float f32x4;

__device__ __forceinline__ float reluf(float x){ return x > 0.f ? x : 0.f; }
__device__ __forceinline__ float lo16(unsigned u){ return __uint_as_float(u << 16); }
__device__ __forceinline__ float hi16(unsigned u){ return __uint_as_float(u & 0xffff0000u); }
__device__ __forceinline__ unsigned short f2bf(float f){
    unsigned u = __float_as_uint(f);
    u += 0x7fffu + ((u >> 16) & 1u);
    return (unsigned short)(u >> 16);
}
__device__ __forceinline__ unsigned packbf(float a, float b){
    return (unsigned)f2bf(a) | ((unsigned)f2bf(b) << 16);
}

// ---------------- CSR build ----------------
__global__ void init_ws_kernel(int* cnt) {
    int i = blockIdx.x*blockDim.x + threadIdx.x;
    if (i < NN) cnt[i] = 0;
}

__global__ void count_kernel(const int* __restrict__ ei, int* __restrict__ cnt) {
    int e = blockIdx.x*blockDim.x + threadIdx.x;
    if (e < NE) atomicAdd(&cnt[ei[NE + e]], 1);
}

__global__ void dinv_kernel(const int* __restrict__ cnt, float* __restrict__ dinv) {
    int i = blockIdx.x*blockDim.x + threadIdx.x;
    if (i < NN) dinv[i] = rsqrtf((float)(cnt[i] + 1));
}

__global__ __launch_bounds__(256) void scan_a_kernel(const int* __restrict__ cnt,
                                                     int* __restrict__ rowptr,
                                                     int* __restrict__ bsum) {
    __shared__ int sh[256];
    int t = threadIdx.x;
    int base = blockIdx.x * 1024 + t*4;
    int v[4]; int s = 0;
    #pragma unroll
    for (int q=0;q<4;q++){ int i = base+q; v[q] = (i < NN) ? (cnt[i] + 1) : 0; s += v[q]; }
    sh[t] = s; __syncthreads();
    for (int off=1; off<256; off<<=1){
        int x = (t>=off) ? sh[t-off] : 0;
        __syncthreads();
        sh[t] += x;
        __syncthreads();
    }
    int run = sh[t] - s;
    #pragma unroll
    for (int q=0;q<4;q++){ int i = base+q; if (i<NN) rowptr[i] = run; run += v[q]; }
    if (t==255) bsum[blockIdx.x] = sh[255];
}

__global__ void scan_b_kernel(int* bsum, int* rowptr, int nb) {
    if (threadIdx.x==0 && blockIdx.x==0){
        int run=0;
        for (int b=0;b<nb;b++){ int x=bsum[b]; bsum[b]=run; run+=x; }
        rowptr[NN] = run;
    }
}

__global__ void scan_c_kernel(int* __restrict__ rowptr, const int* __restrict__ bsum,
                              int* __restrict__ cnt) {
    int i = blockIdx.x*blockDim.x + threadIdx.x;
    if (i < NN){ rowptr[i] += bsum[i >> 10]; cnt[i] = 0; }
}

__global__ void scatter_kernel(const int* __restrict__ ei, const float* __restrict__ dinv,
                               const int* __restrict__ rowptr, int* __restrict__ cnt,
                               int2* __restrict__ coln) {
    int i = blockIdx.x*blockDim.x + threadIdx.x;
    if (i >= NE + NN) return;
    int s, d;
    if (i < NE){ s = ei[i]; d = ei[NE+i]; } else { s = i - NE; d = s; }
    int pos = rowptr[d] + atomicAdd(&cnt[d], 1);
    int2 r; r.x = s; r.y = __float_as_int(dinv[s]*dinv[d]);
    coln[pos] = r;
}

// ---------------- weight prep: transpose + bf16 + even/odd column pairing ----------------
__global__ void prep_weights_kernel(const float* __restrict__ Win, const float* __restrict__ W0,
    const float* __restrict__ W1, const float* __restrict__ Wo1,
    unsigned short* WinT, unsigned short* W0T, unsigned short* W1T, unsigned short* Wo1T)
{
    int b = blockIdx.x, t = threadIdx.x;
    const float* src = (b==0)?Win : (b==1)?W0 : (b==2)?W1 : Wo1;
    unsigned short* dst = (b==0)?WinT : (b==1)?W0T : (b==2)?W1T : Wo1T;
    int K = (b==3)?256:128;
    int total = K*HH;
    for (int i=t; i<total; i+=256){
        int k = i >> 7, c = i & 127;
        int slot = (c & ~31) | ((c & 1) << 4) | ((c & 31) >> 1);
        dst[slot*K + k] = f2bf(src[i]);
    }
}

__global__ void convert_x_kernel(const float* __restrict__ x, unsigned short* __restrict__ xb){
    int i = (blockIdx.x*256 + threadIdx.x)*8;
    float4 f0 = *(const float4*)&x[i];
    float4 f1 = *(const float4*)&x[i+4];
    uint4 r;
    r.x = packbf(f0.x, f0.y);
    r.y = packbf(f0.z, f0.w);
    r.z = packbf(f1.x, f1.y);
    r.w = packbf(f1.z, f1.w);
    *(uint4*)&xb[i] = r;
}

// ---------------- aggregation: outb = A * Xb  (CSR by dst, bf16, 4 edges in flight) ----------------
__global__ __launch_bounds__(256) void aggregate_kernel(const unsigned short* __restrict__ Xb,
    unsigned short* __restrict__ outb,
    const int* __restrict__ rowptr, const int2* __restrict__ coln)
{
    int node = blockIdx.x*8 + (threadIdx.x >> 5);
    int lane = threadIdx.x & 31;
    int c = lane*4;
    int e = rowptr[node], end = rowptr[node+1];
    float a0=0.f,a1=0.f,a2=0.f,a3=0.f;
    for (; e+4 <= end; e += 4){
        int2 m0 = coln[e], m1 = coln[e+1], m2 = coln[e+2], m3 = coln[e+3];
        uint2 v0 = *(const uint2*)&Xb[(size_t)m0.x*HH + c];
        uint2 v1 = *(const uint2*)&Xb[(size_t)m1.x*HH + c];
        uint2 v2 = *(const uint2*)&Xb[(size_t)m2.x*HH + c];
        uint2 v3 = *(const uint2*)&Xb[(size_t)m3.x*HH + c];
        float n0 = __int_as_float(m0.y), n1 = __int_as_float(m1.y);
        float n2 = __int_as_float(m2.y), n3 = __int_as_float(m3.y);
        a0 += n0*lo16(v0.x) + n1*lo16(v1.x) + n2*lo16(v2.x) + n3*lo16(v3.x);
        a1 += n0*hi16(v0.x) + n1*hi16(v1.x) + n2*hi16(v2.x) + n3*hi16(v3.x);
        a2 += n0*lo16(v0.y) + n1*lo16(v1.y) + n2*lo16(v2.y) + n3*lo16(v3.y);
        a3 += n0*hi16(v0.y) + n1*hi16(v1.y) + n2*hi16(v2.y) + n3*hi16(v3.y);
    }
    for (; e < end; ++e){
        int2 m0 = coln[e];
        uint2 v0 = *(const uint2*)&Xb[(size_t)m0.x*HH + c];
        float n0 = __int_as_float(m0.y);
        a0 += n0*lo16(v0.x); a1 += n0*hi16(v0.x);
        a2 += n0*lo16(v0.y); a3 += n0*hi16(v0.y);
    }
    uint2 r;
    r.x = packbf(a0, a1);
    r.y = packbf(a2, a3);
    *(uint2*)&outb[(size_t)node*HH + c] = r;
}

// ---------------- MFMA GEMM [N,128]@[128,128] with fused epilogue ----------------
// MODE 0: v = relu(G+b);           write out32 + outb    (input layer)
// MODE 1: v = Xin32 + relu(G+b);   write out32 + outb    (forward d=0)
// MODE 2: v = out32 + relu(G+b);   write out32 + outb    (forward d>=1, in place)
// MODE 3: v = Xin32 - relu(G+b);   write outb only       (inverse iters 0..6)
// MODE 4: v = Xin32 - relu(G+b);   write out32 + outb    (inverse iter 7: fp32 anchor for next block)
template<int MODE>
__global__ __launch_bounds__(256) void gemm_kernel(
    const unsigned short* __restrict__ Ab,
    const unsigned short* __restrict__ Wt,    // [col slot][128 k] bf16, even/odd paired
    const float* __restrict__ bias,
    const float* __restrict__ Xin32,
    float* __restrict__ out32,
    unsigned short* __restrict__ outb)
{
    int t = threadIdx.x;
    int w = t >> 6, lane = t & 63;
    int l15 = lane & 15, l4 = lane >> 4;
    int colbase = w*32;
    int c0 = colbase + 2*l15;   // this thread's (even) physical column; also owns c0+1

    short8 bfr[4][2];
    #pragma unroll
    for (int kc=0;kc<4;kc++){
        #pragma unroll
        for (int cc=0;cc<2;cc++){
            int cl = colbase + cc*16 + l15;
            bfr[kc][cc] = *(const short8*)&Wt[(size_t)cl*HH + kc*32 + l4*8];
        }
    }
    float2 bb = *(const float2*)&bias[c0];

    int tile0 = blockIdx.x*2;
    #pragma unroll
    for (int u=0;u<2;u++){
        int tt = tile0 + u;
        const unsigned short* ap = &Ab[(size_t)(tt*16 + l15)*HH + l4*8];
        f32x4 acc0 = {0.f,0.f,0.f,0.f};
        f32x4 acc1 = {0.f,0.f,0.f,0.f};
        #pragma unroll
        for (int kc=0;kc<4;kc++){
            short8 a = *(const short8*)(ap + kc*32);
            acc0 = __builtin_amdgcn_mfma_f32_16x16x32_bf16(a, bfr[kc][0], acc0, 0,0,0);
            acc1 = __builtin_amdgcn_mfma_f32_16x16x32_bf16(a, bfr[kc][1], acc1, 0,0,0);
        }
        #pragma unroll
        for (int r=0;r<4;r++){
            int rw = tt*16 + l4*4 + r;
            size_t base = (size_t)rw*HH + c0;
            float v0 = reluf(acc0[r] + bb.x);
            float v1 = reluf(acc1[r] + bb.y);
            if (MODE==1){
                float2 xi = *(const float2*)&Xin32[base];
                v0 += xi.x; v1 += xi.y;
            } else if (MODE==2){
                float2 o = *(const float2*)&out32[base];
                v0 += o.x; v1 += o.y;
            } else if (MODE==3 || MODE==4){
                float2 xi = *(const float2*)&Xin32[base];
                v0 = xi.x - v0; v1 = xi.y - v1;
            }
            if (MODE != 3){
                float2 ov; ov.x = v0; ov.y = v1;
                *(float2*)&out32[base] = ov;
            }
            *(unsigned*)&outb[base] = packbf(v0, v1);
        }
    }
}

// ---------------- fused LN + MLP head (MFMA) ----------------
__global__ __launch_bounds__(256) void final_kernel(
    const unsigned short* __restrict__ zfb, const unsigned short* __restrict__ zbb,
    const float* __restrict__ lng, const float* __restrict__ lnb,
    const unsigned short* __restrict__ Wo1t,  // [128 col slot][256 k] bf16, even/odd paired
    const float* __restrict__ bo1,
    const float* __restrict__ Wo2, const float* __restrict__ bo2,
    float* __restrict__ out)
{
    __shared__ unsigned short zs[64*256];     // 32KB, XOR-swizzled 16B chunks
    __shared__ unsigned short h1s[64*130];    // 16.6KB, stride 130 (odd dwords -> no conflicts)
    __shared__ float w2s[128*OUTD];           // 5KB
    int t = threadIdx.x;
    int node0 = blockIdx.x * 64;

    // ---- phase 0: coalesced global loads, swizzled LDS writes ----
    #pragma unroll
    for (int it=0; it<4; ++it){
        int f = it*256 + t;              // 0..1023 : row = f>>4 (0..63), chunk = f&15
        int row = f >> 4, cc = f & 15;
        uint4 v  = *(const uint4*)&zfb[(size_t)(node0+row)*HH + cc*8];
        *(uint4*)&zs[row*256 + ((cc       ) ^ (row&7))*8] = v;
        uint4 v2 = *(const uint4*)&zbb[(size_t)(node0+row)*HH + cc*8];
        *(uint4*)&zs[row*256 + ((16 + cc  ) ^ (row&7))*8] = v2;
    }
    for (int i=t; i<HH*OUTD; i+=256) w2s[i] = Wo2[i];
    __syncthreads();

    // ---- phase 1: LayerNorm in LDS (4 threads per node), in-place ----
    {
        int n = t >> 2, q = t & 3;
        uint4 pk[8];
        float s = 0.f, sq = 0.f;
        #pragma unroll
        for (int m=0;m<8;m++){
            int ch = q*8 + m;
            pk[m] = *(const uint4*)&zs[n*256 + (ch ^ (n&7))*8];
            float f0=lo16(pk[m].x), f1=hi16(pk[m].x), f2=lo16(pk[m].y), f3=hi16(pk[m].y);
            float f4=lo16(pk[m].z), f5=hi16(pk[m].z), f6=lo16(pk[m].w), f7=hi16(pk[m].w);
            s  += f0+f1+f2+f3+f4+f5+f6+f7;
            sq += f0*f0+f1*f1+f2*f2+f3*f3+f4*f4+f5*f5+f6*f6+f7*f7;
        }
        s  += __shfl_xor(s,1);  s  += __shfl_xor(s,2);
        sq += __shfl_xor(sq,1); sq += __shfl_xor(sq,2);
        float mu = s * (1.f/256.f);
        float var = sq * (1.f/256.f) - mu*mu;
        float rs = rsqrtf(var + 1e-5f);
        #pragma unroll
        for (int m=0;m<8;m++){
            int ch = q*8 + m;
            int cb = ch*8;
            float4 g0 = *(const float4*)&lng[cb];
            float4 g1 = *(const float4*)&lng[cb+4];
            float4 b0 = *(const float4*)&lnb[cb];
            float4 b1 = *(const float4*)&lnb[cb+4];
            uint4 r;
            r.x = packbf((lo16(pk[m].x)-mu)*rs*g0.x+b0.x, (hi16(pk[m].x)-mu)*rs*g0.y+b0.y);
            r.y = packbf((lo16(pk[m].y)-mu)*rs*g0.z+b0.z, (hi16(pk[m].y)-mu)*rs*g0.w+b0.w);
            r.z = packbf((lo16(pk[m].z)-mu)*rs*g1.x+b1.x, (hi16(pk[m].z)-mu)*rs*g1.y+b1.y);
            r.w = packbf((lo16(pk[m].w)-mu)*rs*g1.z+b1.z, (hi16(pk[m].w)-mu)*rs*g1.w+b1.w);
            *(uint4*)&zs[n*256 + (ch ^ (n&7))*8] = r;
        }
    }
    __syncthreads();

    // ---- phase 2: h1 = relu(z @ Wo1 + bo1) via MFMA, paired-column output ----
    {
        int w = t >> 6, lane = t & 63;
        int l15 = lane & 15, l4 = lane >> 4;
        int c0 = w*32 + 2*l15;
        short8 bfr[8][2];
        #pragma unroll
        for (int kc=0;kc<8;kc++){
            #pragma unroll
            for (int cc=0;cc<2;cc++){
                int cl = w*32 + cc*16 + l15;
                bfr[kc][cc] = *(const short8*)&Wo1t[(size_t)cl*256 + kc*32 + l4*8];
            }
        }
        float2 bb = *(const float2*)&bo1[c0];
        #pragma unroll
        for (int rt=0;rt<4;rt++){
            f32x4 acc0 = {0.f,0.f,0.f,0.f};
            f32x4 acc1 = {0.f,0.f,0.f,0.f};
            int row = rt*16 + l15;
            int rsw = (row&7)<<3;
            #pragma unroll
            for (int kc=0;kc<8;kc++){
                int idx = row*256 + kc*32 + l4*8;
                short8 a = *(const short8*)&zs[idx ^ rsw];
                acc0 = __builtin_amdgcn_mfma_f32_16x16x32_bf16(a, bfr[kc][0], acc0, 0,0,0);
                acc1 = __builtin_amdgcn_mfma_f32_16x16x32_bf16(a, bfr[kc][1], acc1, 0,0,0);
            }
            #pragma unroll
            for (int r=0;r<4;r++){
                int rw = rt*16 + l4*4 + r;
                *(unsigned*)&h1s[rw*130 + c0] =
                    packbf(reluf(acc0[r] + bb.x), reluf(acc1[r] + bb.y));
            }
        }
    }
    __syncthreads();

    // ---- phase 3: out = h1 @ Wo2 + bo2 (128 -> 10) ----
    for (int item = t; item < 64*OUTD; item += 256){
        int n = item / OUTD, o = item - n*OUTD;
        const unsigned short* hr = &h1s[n*130];
        float s = bo2[o];
        #pragma unroll 16
        for (int k=0;k<HH;k+=2){
            unsigned u = *(const unsigned*)&hr[k];
            s += lo16(u)*w2s[k*OUTD+o] + hi16(u)*w2s[(k+1)*OUTD+o];
        }
        out[(size_t)(node0+n)*OUTD + o] = s;
    }
}

// ---------------- host ----------------
extern "C" void kernel_launch(void* const* d_in, const int* in_sizes, int n_in,
                              void* d_out, int out_size, void* d_ws, size_t ws_size,
                              hipStream_t stream)
{
    const float* x    = (const float*)d_in[0];
    const int*   ei   = (const int*)d_in[1];
    const float* W_in = (const float*)d_in[2];
    const float* b_in = (const float*)d_in[3];
    const float* W0   = (const float*)d_in[4];
    const float* b0   = (const float*)d_in[5];
    const float* W1   = (const float*)d_in[6];
    const float* b1   = (const float*)d_in[7];
    const float* lng  = (const float*)d_in[8];
    const float* lnb  = (const float*)d_in[9];
    const float* Wo1  = (const float*)d_in[10];
    const float* bo1  = (const float*)d_in[11];
    const float* Wo2  = (const float*)d_in[12];
    const float* bo2  = (const float*)d_in[13];
    float* out = (float*)d_out;

    char* p = (char*)d_ws;
    auto alloc = [&](size_t bytes)->char* {
        char* r = p; p += (bytes + 255) & ~(size_t)255; return r;
    };
    float* dinv   = (float*)alloc((size_t)NN*4);
    int*   cnt    = (int*)  alloc((size_t)NN*4);
    int*   rowptr = (int*)  alloc((size_t)(NN+1)*4);
    int*   bsum   = (int*)  alloc(64*4);
    int2*  coln   = (int2*) alloc((size_t)(NE+NN)*8);
    unsigned short* x_b   = (unsigned short*)alloc((size_t)NN*HH*2);
    unsigned short* agg_b = (unsigned short*)alloc((size_t)NN*HH*2);
    unsigned short* WinT  = (unsigned short*)alloc((size_t)HH*HH*2);
    unsigned short* W0T   = (unsigned short*)alloc((size_t)HH*HH*2);
    unsigned short* W1T   = (unsigned short*)alloc((size_t)HH*HH*2);
    unsigned short* Wo1T  = (unsigned short*)alloc((size_t)256*HH*2);
    float* h     = (float*)alloc((size_t)NN*HH*4);
    float* zf    = (float*)alloc((size_t)NN*HH*4);
    float* inv32 = (float*)alloc((size_t)NN*HH*4);
    unsigned short* h_b   = (unsigned short*)alloc((size_t)NN*HH*2);
    unsigned short* zf_b  = (unsigned short*)alloc((size_t)NN*HH*2);
    unsigned short* bufA  = (unsigned short*)alloc((size_t)NN*HH*2);
    unsigned short* bufB  = (unsigned short*)alloc((size_t)NN*HH*2);

    init_ws_kernel<<<(NN+255)/256, 256, 0, stream>>>(cnt);
    count_kernel<<<(NE+255)/256, 256, 0, stream>>>(ei, cnt);
    dinv_kernel<<<(NN+255)/256, 256, 0, stream>>>(cnt, dinv);
    int nb = (NN+1023)/1024;
    scan_a_kernel<<<nb, 256, 0, stream>>>(cnt, rowptr, bsum);
    scan_b_kernel<<<1, 64, 0, stream>>>(bsum, rowptr, nb);
    scan_c_kernel<<<(NN+255)/256, 256, 0, stream>>>(rowptr, bsum, cnt);
    scatter_kernel<<<(NE+NN+255)/256, 256, 0, stream>>>(ei, dinv, rowptr, cnt, coln);
    convert_x_kernel<<<2500, 256, 0, stream>>>(x, x_b);
    prep_weights_kernel<<<4, 256, 0, stream>>>(W_in, W0, W1, Wo1, WinT, W0T, W1T, Wo1T);

    const int GG = 1250;   // 2500 tiles, 2 per block

    // h = relu(x @ W_in + b_in)  -> fp32 + bf16
    gemm_kernel<0><<<GG, 256, 0, stream>>>(x_b, WinT, b_in, nullptr, h, h_b);

    // forward residual blocks (fp32 accumulator zf, bf16 mirror zf_b)
    for (int d=0; d<4; ++d){
        const unsigned short* Wd = (d & 1) ? W1T : W0T;
        const float* bd = (d & 1) ? b1 : b0;
        const unsigned short* src_b = (d == 0) ? h_b : zf_b;
        aggregate_kernel<<<NN/8, 256, 0, stream>>>(src_b, agg_b, rowptr, coln);
        if (d == 0)
            gemm_kernel<1><<<GG, 256, 0, stream>>>(agg_b, Wd, bd, h, zf, zf_b);
        else
            gemm_kernel<2><<<GG, 256, 0, stream>>>(agg_b, Wd, bd, nullptr, zf, zf_b);
    }

    // inverse fixed-point blocks: 8 iterations each, bf16 intermediate state,
    // fp32 anchor I32 carried across blocks (this is the precision-critical path)
    unsigned short* bb3[3] = {h_b, bufA, bufB};
    unsigned short* curb = h_b;     // bf16 mirror of block input
    float* I32 = h;                 // fp32 block anchor
    float* J32 = inv32;             // spare for next anchor
    for (int blk=0; blk<4; ++blk){
        const unsigned short* Wi = (blk & 1) ? W0T : W1T;
        const float* bi = (blk & 1) ? b0 : b1;
        unsigned short *p0=nullptr, *p1=nullptr;
        for (int q=0;q<3;q++){
            if (bb3[q]!=curb){ if(!p0) p0=bb3[q]; else p1=bb3[q]; }
        }
        const unsigned short* cur = curb;
        for (int tt=0; tt<8; ++tt){
            aggregate_kernel<<<NN/8, 256, 0, stream>>>(cur, agg_b, rowptr, coln);
            unsigned short* nxt = (cur == p0) ? p1 : p0;
            if (tt < 7)
                gemm_kernel<3><<<GG, 256, 0, stream>>>(agg_b, Wi, bi, I32, nullptr, nxt);
            else
                gemm_kernel<4><<<GG, 256, 0, stream>>>(agg_b, Wi, bi, I32, J32, nxt);
            cur = nxt;
        }
        curb = (unsigned short*)cur;
        float* tf = I32; I32 = J32; J32 = tf;
    }

    final_kernel<<<NN/64, 256, 0, stream>>>(zf_b, curb, lng, lnb, Wo1T, bo1, Wo2, bo2, out);
}